// Round 15
// baseline (4312.415 us; speedup 1.0000x reference)
//
#include <hip/hip_runtime.h>
#include <math.h>

typedef unsigned short u16;
typedef __attribute__((ext_vector_type(8))) short short8;   // 8 bf16 (4 VGPRs)
typedef __attribute__((ext_vector_type(4))) float f32x4;

#define BB 2
#define SS 1024
#define LL 12
#define HH 12
#define DD 768
#define FFF 3072
#define MOTIF 414
#define HCAT (DD + MOTIF)
#define W1 256
#define NEGV -1e9f
#define EPS 1e-5f
#define SCALE 0.125f
#define LD3 2304            // 3*768, QKV buffer row stride (q|k|v)
#define WL_ELE 7077888      // u16 per layer: 4 DDxDD + Wi + Wo2 (14155776 B)

// ---------- bf16 helpers ----------
__device__ __forceinline__ float bf2f(u16 u) {
    union { unsigned i; float f; } x; x.i = ((unsigned)u) << 16; return x.f;
}
__device__ __forceinline__ u16 f2bf(float f) {
    union { float f; unsigned i; } x; x.f = f;
    unsigned r = x.i + 0x7fffu + ((x.i >> 16) & 1u);   // RNE
    return (u16)(r >> 16);
}

// async global->LDS, 16B per lane; lds dest must be wave-uniform base
__device__ __forceinline__ void gld16(const u16* g, u16* l) {
    __builtin_amdgcn_global_load_lds((const __attribute__((address_space(1))) void*)g,
                                     (__attribute__((address_space(3))) void*)l, 16, 0, 0);
}

// ---------------- block reduction helper (blockDim.x == 256) ----------------
__device__ __forceinline__ float block_reduce_sum(float v, float* red) {
    int t = threadIdx.x;
    red[t] = v; __syncthreads();
    #pragma unroll
    for (int s = 128; s > 0; s >>= 1) {
        if (t < s) red[t] += red[t + s];
        __syncthreads();
    }
    float r = red[0]; __syncthreads();
    return r;
}

// ---------------- embedding + LN (writes f32 X and bf16 Xb) ----------------
__global__ __launch_bounds__(256) void embed_ln_kernel(
    const int* __restrict__ ids, const float* __restrict__ ew,
    const float* __restrict__ ep, const float* __restrict__ et,
    const float* __restrict__ gs, const float* __restrict__ gb,
    float* __restrict__ X, u16* __restrict__ Xb) {
    __shared__ float red[256];
    int row = blockIdx.x;
    int s = row % SS;
    int id = ids[row];
    int t = threadIdx.x;
    float v[3];
    float sum = 0.f;
    #pragma unroll
    for (int i = 0; i < 3; ++i) {
        int d = t + 256 * i;
        float x = ew[(size_t)id * DD + d] + ep[(size_t)(s + 2) * DD + d] + et[d];
        v[i] = x; sum += x;
    }
    sum = block_reduce_sum(sum, red);
    float m = sum * (1.f / DD);
    float sq = 0.f;
    #pragma unroll
    for (int i = 0; i < 3; ++i) { float c = v[i] - m; sq += c * c; }
    sq = block_reduce_sum(sq, red);
    float inv = rsqrtf(sq * (1.f / DD) + EPS);
    #pragma unroll
    for (int i = 0; i < 3; ++i) {
        int d = t + 256 * i;
        float o = (v[i] - m) * inv * gs[d] + gb[d];
        X[(size_t)row * DD + d] = o;
        Xb[(size_t)row * DD + d] = f2bf(o);
    }
}

// ---------------- residual add + LN: X = LN(X + sum_{p<NT} T[p]); writes f32 + bf16 ----
__global__ __launch_bounds__(256) void add_ln_kernel(
    float* __restrict__ X, u16* __restrict__ Xb,
    const float* __restrict__ Tbase, int NT,
    const float* __restrict__ gs, const float* __restrict__ gb) {
    __shared__ float red[256];
    int row = blockIdx.x;
    int t = threadIdx.x;
    const size_t MN = (size_t)BB * SS * DD;
    float v[3];
    float sum = 0.f;
    #pragma unroll
    for (int i = 0; i < 3; ++i) {
        int d = t + 256 * i;
        size_t idx = (size_t)row * DD + d;
        float x = X[idx];
        for (int p = 0; p < NT; ++p) x += Tbase[p * MN + idx];
        v[i] = x; sum += x;
    }
    sum = block_reduce_sum(sum, red);
    float m = sum * (1.f / DD);
    float sq = 0.f;
    #pragma unroll
    for (int i = 0; i < 3; ++i) { float c = v[i] - m; sq += c * c; }
    sq = block_reduce_sum(sq, red);
    float inv = rsqrtf(sq * (1.f / DD) + EPS);
    #pragma unroll
    for (int i = 0; i < 3; ++i) {
        int d = t + 256 * i;
        float o = (v[i] - m) * inv * gs[d] + gb[d];
        X[(size_t)row * DD + d] = o;
        Xb[(size_t)row * DD + d] = f2bf(o);
    }
}

// ---------------- weight convert+transpose, 64k x 64n tile per block ----------------
// tiles: [0,576) four DDxDD {q,k,v,o} -> Wt4 ; [576,1152) Wi -> Wti[3072][768] ;
// [1152,1728) Wo2 -> Wto2[768][3072].  blockIdx.y = layer (LAYERED) or 0.
template <int LAYERED>
__global__ __launch_bounds__(256) void conv_all_kernel(
    const float* __restrict__ Wqp, const float* __restrict__ Wkp,
    const float* __restrict__ Wvp, const float* __restrict__ Wop,
    const float* __restrict__ Wip, const float* __restrict__ Wo2p,
    u16* __restrict__ WtBase) {
    __shared__ float Tt[64][65];
    int l = LAYERED ? blockIdx.y : 0;
    size_t oDD = (size_t)l * DD * DD;
    size_t oFF = (size_t)l * DD * FFF;
    u16* Wt4  = WtBase + (size_t)l * WL_ELE;
    u16* Wti  = Wt4 + 4 * DD * DD;
    u16* Wto2 = Wti + FFF * DD;
    int tid = blockIdx.x;
    const float* W; u16* Wt; int Nd, Kd, n0, k0;
    if (tid < 576) {
        int z = tid / 144, rem = tid % 144;
        const float* w4[4] = {Wqp + oDD, Wkp + oDD, Wvp + oDD, Wop + oDD};
        W = w4[z];
        Wt = Wt4 + (size_t)z * DD * DD;
        Nd = DD; Kd = DD; n0 = (rem % 12) * 64; k0 = (rem / 12) * 64;
    } else if (tid < 1152) {
        int i = tid - 576;
        W = Wip + oFF; Wt = Wti; Nd = FFF; Kd = DD; n0 = (i % 48) * 64; k0 = (i / 48) * 64;
    } else {
        int i = tid - 1152;
        W = Wo2p + oFF; Wt = Wto2; Nd = DD; Kd = FFF; n0 = (i % 12) * 64; k0 = (i / 12) * 64;
    }
    int t = threadIdx.x;
    {
        int rbase = t >> 4, c = (t & 15) * 4;
        #pragma unroll
        for (int i = 0; i < 4; ++i) {
            int r = rbase + i * 16;
            float4 v = *(const float4*)(W + (size_t)(k0 + r) * Nd + n0 + c);
            Tt[r][c + 0] = v.x; Tt[r][c + 1] = v.y;
            Tt[r][c + 2] = v.z; Tt[r][c + 3] = v.w;
        }
    }
    __syncthreads();
    {
        int nbase = t >> 3, kk = (t & 7) * 8;
        #pragma unroll
        for (int i = 0; i < 2; ++i) {
            int n = nbase + i * 32;
            union { uint4 v; u16 e[8]; } wv;
            #pragma unroll
            for (int j = 0; j < 8; ++j) wv.e[j] = f2bf(Tt[kk + j][n]);
            *(uint4*)&Wt[(size_t)(n0 + n) * Kd + k0 + kk] = wv.v;
        }
    }
}

// ---------------- bias concat for batched QKV gemm: bcat[l][3*768] ----------------
__global__ __launch_bounds__(256) void bcat_kernel(
    const float* __restrict__ bq, const float* __restrict__ bk,
    const float* __restrict__ bv, float* __restrict__ bcat) {
    int tid = blockIdx.x * 256 + threadIdx.x;
    if (tid >= LL * LD3) return;
    int l = tid / LD3, r = tid % LD3, z = r / DD, j = r % DD;
    const float* src = (z == 0) ? bq : (z == 1) ? bk : bv;
    bcat[tid] = src[l * DD + j];
}

// ---------------- bf16 MFMA GEMM, 2-deep counted-vmcnt pipeline (R8-proven) ----------
#define STAGE(j, buf)                                                                   \
    do {                                                                                \
        int _k0 = (j) << 5;                                                             \
        _Pragma("unroll")                                                               \
        for (int _op = 0; _op < 2; ++_op) {                                             \
            int _rc = rA + _op * 16;                                                    \
            int _r = _rc + rr;                                                          \
            gld16(A  + (size_t)(bm + _r) * K + kbeg + _k0 + ((s4 ^ (_r & 3)) * 8),      \
                  &As[buf][_rc * 32]);                                                  \
            gld16(Bt + (size_t)(bn + _r) * K + kbeg + _k0 + ((s4 ^ (_r & 3)) * 8),      \
                  &Bs[buf][_rc * 32]);                                                  \
        }                                                                               \
    } while (0)

template <int ACT, int OBF>
__global__ __launch_bounds__(256) void gemm_bf16(
    const u16* __restrict__ A, const u16* __restrict__ Bt,
    const float* __restrict__ bias, void* __restrict__ Cout,
    int M, int N, int K, int Ksplit) {
    __shared__ __align__(16) u16 As[2][128 * 32];
    __shared__ __align__(16) u16 Bs[2][128 * 32];
    int z = blockIdx.z;
    int kbeg = z * Ksplit;
    int kend = kbeg + Ksplit; if (kend > K) kend = K;
    int t = threadIdx.x, lane = t & 63, wv = t >> 6;
    int bm = blockIdx.y * 128, bn = blockIdx.x * 128;
    int wm = wv >> 1, wn = wv & 1;
    int h = lane >> 4, q15 = lane & 15;
    int rA = wv * 32;
    int rr = lane >> 2, s4 = lane & 3;
    f32x4 acc[4][4];
    #pragma unroll
    for (int i = 0; i < 4; ++i)
        #pragma unroll
        for (int j = 0; j < 4; ++j) { acc[i][j][0] = 0.f; acc[i][j][1] = 0.f; acc[i][j][2] = 0.f; acc[i][j][3] = 0.f; }

    int nk = (kend - kbeg) >> 5;
    STAGE(0, 0);
    if (nk > 1) STAGE(1, 1);
    int cur = 0;
    for (int i = 0; i < nk - 1; ++i) {
        asm volatile("s_waitcnt vmcnt(4)" ::: "memory");
        __builtin_amdgcn_s_barrier();
        short8 af[4], bfr[4];
        #pragma unroll
        for (int mf = 0; mf < 4; ++mf) {
            int row = wm * 64 + mf * 16 + q15;
            af[mf] = *(const short8*)&As[cur][row * 32 + ((h ^ (row & 3)) * 8)];
        }
        #pragma unroll
        for (int nf = 0; nf < 4; ++nf) {
            int row = wn * 64 + nf * 16 + q15;
            bfr[nf] = *(const short8*)&Bs[cur][row * 32 + ((h ^ (row & 3)) * 8)];
        }
        asm volatile("s_waitcnt lgkmcnt(0)" ::: "memory");
        __builtin_amdgcn_sched_barrier(0);
        __builtin_amdgcn_s_barrier();
        __builtin_amdgcn_sched_barrier(0);
        if (i + 2 < nk) STAGE(i + 2, cur);
        #pragma unroll
        for (int mf = 0; mf < 4; ++mf)
            #pragma unroll
            for (int nf = 0; nf < 4; ++nf)
                acc[mf][nf] = __builtin_amdgcn_mfma_f32_16x16x32_bf16(af[mf], bfr[nf], acc[mf][nf], 0, 0, 0);
        cur ^= 1;
    }
    asm volatile("s_waitcnt vmcnt(0)" ::: "memory");
    __builtin_amdgcn_s_barrier();
    {
        short8 af[4], bfr[4];
        #pragma unroll
        for (int mf = 0; mf < 4; ++mf) {
            int row = wm * 64 + mf * 16 + q15;
            af[mf] = *(const short8*)&As[cur][row * 32 + ((h ^ (row & 3)) * 8)];
        }
        #pragma unroll
        for (int nf = 0; nf < 4; ++nf) {
            int row = wn * 64 + nf * 16 + q15;
            bfr[nf] = *(const short8*)&Bs[cur][row * 32 + ((h ^ (row & 3)) * 8)];
        }
        #pragma unroll
        for (int mf = 0; mf < 4; ++mf)
            #pragma unroll
            for (int nf = 0; nf < 4; ++nf)
                acc[mf][nf] = __builtin_amdgcn_mfma_f32_16x16x32_bf16(af[mf], bfr[nf], acc[mf][nf], 0, 0, 0);
    }
    float* Cf = (float*)Cout + (size_t)z * M * N;
    u16*   Cb = (u16*)Cout;
    #pragma unroll
    for (int mf = 0; mf < 4; ++mf) {
        int mbase = bm + wm * 64 + mf * 16 + h * 4;
        #pragma unroll
        for (int nf = 0; nf < 4; ++nf) {
            int n = bn + wn * 64 + nf * 16 + q15;
            float bv = 0.f;
            if (z == 0) bv = bias[n];
            #pragma unroll
            for (int rg = 0; rg < 4; ++rg) {
                float val = acc[mf][nf][rg] + bv;
                if (ACT == 1) val = 0.5f * val * (1.f + erff(val * 0.70710678118654752f));
                if (OBF) Cb[(size_t)(mbase + rg) * N + n] = f2bf(val);
                else     Cf[(size_t)(mbase + rg) * N + n] = val;
            }
        }
    }
}

// ---------------- fused local-window flash attention (MFMA), R8-proven ----------------
// one block per (b, h, 64-query tile); QKV bf16 row-major [B*S][2304] (q|k|v)
__global__ __launch_bounds__(256) void attn_local_mfma(
    const u16* __restrict__ QKV, const int* __restrict__ mask,
    u16* __restrict__ AO) {
    __shared__ __align__(16) u16 Qs[64 * 64];
    __shared__ __align__(16) u16 Ks[64 * 64];
    __shared__ __align__(16) u16 Vst[64 * 64];
    __shared__ __align__(16) u16 Pld[4][16 * 64];
    __shared__ float msk[64];
    int bid = blockIdx.x;
    int qt = bid & 15;
    int hh = (bid >> 4) % HH;
    int b  = bid / (16 * HH);
    int t = threadIdx.x, lane = t & 63, wv = t >> 6;
    int h = lane >> 4, q15 = lane & 15;
    int i0 = qt * 64;

    #pragma unroll
    for (int op = 0; op < 2; ++op) {
        int r = wv * 16 + op * 8 + (lane >> 3), s = lane & 7;
        gld16(QKV + (size_t)(b * SS + i0 + r) * LD3 + hh * 64 + ((s ^ (r & 7)) * 8),
              &Qs[(wv * 16 + op * 8) * 64]);
    }
    __syncthreads();
    short8 bq[2];
    {
        int qrow = wv * 16 + q15;
        #pragma unroll
        for (int ks = 0; ks < 2; ++ks)
            bq[ks] = *(const short8*)&Qs[qrow * 64 + (((ks * 4 + h) ^ (qrow & 7)) * 8)];
    }

    float mrun = -3e38f, lrun = 0.f;
    f32x4 o[4];
    #pragma unroll
    for (int nf = 0; nf < 4; ++nf) { o[nf][0] = 0.f; o[nf][1] = 0.f; o[nf][2] = 0.f; o[nf][3] = 0.f; }

    int jlo = i0 - W1; if (jlo < 0) jlo = 0;
    int jend = i0 + 64 + W1; if (jend > SS) jend = SS;
    int hasCLS = (jlo > 0) ? 1 : 0;
    int nt = hasCLS + (jend - jlo) / 64;
    int iq = i0 + wv * 16 + q15;

    for (int tt = 0; tt < nt; ++tt) {
        int base = (hasCLS && tt == 0) ? 0 : jlo + (tt - hasCLS) * 64;
        if (tt > 0) __syncthreads();
        #pragma unroll
        for (int op = 0; op < 2; ++op) {
            int r = wv * 16 + op * 8 + (lane >> 3), s = lane & 7;
            gld16(QKV + (size_t)(b * SS + base + r) * LD3 + 768 + hh * 64 + ((s ^ (r & 7)) * 8),
                  &Ks[(wv * 16 + op * 8) * 64]);
        }
        {
            int k2 = t & 31, dsec = t >> 5;
            const u16* vp = QKV + (size_t)(b * SS + base + 2 * k2) * LD3 + 1536 + hh * 64 + dsec * 8;
            union { uint4 v; u16 e[8]; } r0, r1;
            r0.v = *(const uint4*)vp;
            r1.v = *(const uint4*)(vp + LD3);
            int slot = k2 >> 2;
            #pragma unroll
            for (int j = 0; j < 8; ++j) {
                int d = dsec * 8 + j;
                unsigned val = (unsigned)r0.e[j] | ((unsigned)r1.e[j] << 16);
                *(unsigned*)&Vst[d * 64 + ((slot ^ (d & 7)) * 8) + ((2 * k2) & 7)] = val;
            }
        }
        if (t < 64) msk[t] = (float)mask[b * SS + base + t];
        __syncthreads();

        f32x4 sacc[4];
        #pragma unroll
        for (int kf = 0; kf < 4; ++kf) { sacc[kf][0] = 0.f; sacc[kf][1] = 0.f; sacc[kf][2] = 0.f; sacc[kf][3] = 0.f; }
        #pragma unroll
        for (int ks = 0; ks < 2; ++ks) {
            #pragma unroll
            for (int kf = 0; kf < 4; ++kf) {
                int krow = kf * 16 + q15;
                short8 afr = *(const short8*)&Ks[krow * 64 + (((ks * 4 + h) ^ (krow & 7)) * 8)];
                sacc[kf] = __builtin_amdgcn_mfma_f32_16x16x32_bf16(afr, bq[ks], sacc[kf], 0, 0, 0);
            }
        }
        float pv[4][4];
        float tmax = -3e38f;
        #pragma unroll
        for (int kf = 0; kf < 4; ++kf) {
            #pragma unroll
            for (int rg = 0; rg < 4; ++rg) {
                int kl = kf * 16 + h * 4 + rg;
                int key = base + kl;
                int dj = iq - key; int adj = dj < 0 ? -dj : dj;
                bool valid = ((adj <= W1) || (key == 0)) && (msk[kl] != 0.f);
                float s = valid ? sacc[kf][rg] * SCALE : NEGV;
                pv[kf][rg] = s;
                tmax = fmaxf(tmax, s);
            }
        }
        tmax = fmaxf(tmax, __shfl_xor(tmax, 16));
        tmax = fmaxf(tmax, __shfl_xor(tmax, 32));
        float mnew = fmaxf(mrun, tmax);
        float fac = __expf(mrun - mnew);
        mrun = mnew;
        float psum = 0.f;
        #pragma unroll
        for (int kf = 0; kf < 4; ++kf)
            #pragma unroll
            for (int rg = 0; rg < 4; ++rg) {
                float p = __expf(pv[kf][rg] - mnew);
                pv[kf][rg] = p; psum += p;
            }
        psum += __shfl_xor(psum, 16);
        psum += __shfl_xor(psum, 32);
        lrun = lrun * fac + psum;
        #pragma unroll
        for (int kf = 0; kf < 4; ++kf) {
            unsigned lo = (unsigned)f2bf(pv[kf][0]) | ((unsigned)f2bf(pv[kf][1]) << 16);
            unsigned hi = (unsigned)f2bf(pv[kf][2]) | ((unsigned)f2bf(pv[kf][3]) << 16);
            int slot = 2 * kf + (h >> 1);
            uint2 w; w.x = lo; w.y = hi;
            *(uint2*)&Pld[wv][q15 * 64 + ((slot ^ (q15 & 7)) * 8) + 4 * (h & 1)] = w;
        }
        float fo0 = __shfl(fac, (h * 4 + 0) | (lane & 48));
        float fo1 = __shfl(fac, (h * 4 + 1) | (lane & 48));
        float fo2 = __shfl(fac, (h * 4 + 2) | (lane & 48));
        float fo3 = __shfl(fac, (h * 4 + 3) | (lane & 48));
        #pragma unroll
        for (int nf = 0; nf < 4; ++nf) {
            o[nf][0] *= fo0; o[nf][1] *= fo1; o[nf][2] *= fo2; o[nf][3] *= fo3;
        }
        asm volatile("s_waitcnt lgkmcnt(0)" ::: "memory");
        #pragma unroll
        for (int ks = 0; ks < 2; ++ks) {
            short8 ap = *(const short8*)&Pld[wv][q15 * 64 + (((ks * 4 + h) ^ (q15 & 7)) * 8)];
            #pragma unroll
            for (int nf = 0; nf < 4; ++nf) {
                int d = nf * 16 + q15;
                short8 bvf = *(const short8*)&Vst[d * 64 + (((ks * 4 + h) ^ (d & 7)) * 8)];
                o[nf] = __builtin_amdgcn_mfma_f32_16x16x32_bf16(ap, bvf, o[nf], 0, 0, 0);
            }
        }
    }
    float linv = 1.f / lrun;
    float g0 = __shfl(linv, (h * 4 + 0) | (lane & 48));
    float g1 = __shfl(linv, (h * 4 + 1) | (lane & 48));
    float g2 = __shfl(linv, (h * 4 + 2) | (lane & 48));
    float g3 = __shfl(linv, (h * 4 + 3) | (lane & 48));
    size_t rb = (size_t)(b * SS + i0 + wv * 16 + h * 4);
    #pragma unroll
    for (int nf = 0; nf < 4; ++nf) {
        int d = hh * 64 + nf * 16 + q15;
        AO[(rb + 0) * DD + d] = f2bf(o[nf][0] * g0);
        AO[(rb + 1) * DD + d] = f2bf(o[nf][1] * g1);
        AO[(rb + 2) * DD + d] = f2bf(o[nf][2] * g2);
        AO[(rb + 3) * DD + d] = f2bf(o[nf][3] * g3);
    }
}

// ---------------- rank-1 global (CLS) attention, all f32, no KG/VG needed ----------
// score_j = x_j . u + c   with u = Wkg[:,hs] @ qg, c = qg . bkg[hs]
// og      = (X^T p) @ Wvg[:,hs] + bvg[hs]
// one block per (b, h), 512 threads; overwrites AO row 0
__global__ __launch_bounds__(512) void attn_global_kernel(
    const float* __restrict__ Xf, const float* __restrict__ Wqg,
    const float* __restrict__ bqg, const float* __restrict__ Wkg,
    const float* __restrict__ bkg, const float* __restrict__ Wvg,
    const float* __restrict__ bvg, const int* __restrict__ mask,
    u16* __restrict__ AO) {
    __shared__ float x0[DD];
    __shared__ float qv[64];
    __shared__ float uu[DD];
    __shared__ float wvec[DD];
    __shared__ float sc[SS];
    __shared__ float red[512];
    __shared__ float part[8][64];
    __shared__ float cbias;
    int b = blockIdx.x / HH, hh = blockIdx.x % HH;
    int t = threadIdx.x;
    const float* Xrow = Xf + (size_t)b * SS * DD;
    for (int i = t; i < DD; i += 512) x0[i] = Xrow[i];
    __syncthreads();
    // qg GEMV, 8-way k-split (pre-scaled)
    {
        int d = t & 63, p = t >> 6;
        float acc = 0.f;
        int k0 = p * 96;
        #pragma unroll 8
        for (int k = k0; k < k0 + 96; ++k)
            acc += x0[k] * Wqg[(size_t)k * DD + hh * 64 + d];
        part[p][d] = acc;
    }
    __syncthreads();
    if (t < 64) {
        float s = bqg[hh * 64 + t];
        #pragma unroll
        for (int p = 0; p < 8; ++p) s += part[p][t];
        qv[t] = s * SCALE;
    }
    __syncthreads();
    // u[k] = Wkg[k, hs] . qv ; c = qv . bkg[hs]
    for (int k = t; k < DD; k += 512) {
        const float* wr = Wkg + (size_t)k * DD + hh * 64;
        float acc = 0.f;
        #pragma unroll
        for (int d = 0; d < 64; d += 4) {
            float4 w4 = *(const float4*)(wr + d);
            acc += w4.x * qv[d] + w4.y * qv[d + 1] + w4.z * qv[d + 2] + w4.w * qv[d + 3];
        }
        uu[k] = acc;
    }
    if (t < 64) part[0][t] = qv[t] * bkg[hh * 64 + t];
    __syncthreads();
    if (t == 0) {
        float c = 0.f;
        #pragma unroll
        for (int d = 0; d < 64; ++d) c += part[0][d];
        cbias = c;
    }
    __syncthreads();
    // scores
    for (int j = t; j < SS; j += 512) {
        const float* xr = Xrow + (size_t)j * DD;
        float acc = 0.f;
        #pragma unroll 4
        for (int d = 0; d < DD; d += 4) {
            float4 xv = *(const float4*)(xr + d);
            acc += xv.x * uu[d] + xv.y * uu[d + 1] + xv.z * uu[d + 2] + xv.w * uu[d + 3];
        }
        sc[j] = mask[b * SS + j] ? (acc + cbias) : NEGV;
    }
    __syncthreads();
    // softmax over 1024 (keep sc unnormalized exp; divide at the end)
    float mx = fmaxf(sc[t], sc[t + 512]);
    red[t] = mx; __syncthreads();
    #pragma unroll
    for (int s = 256; s > 0; s >>= 1) {
        if (t < s) red[t] = fmaxf(red[t], red[t + s]);
        __syncthreads();
    }
    mx = red[0]; __syncthreads();
    float e0 = __expf(sc[t] - mx), e1 = __expf(sc[t + 512] - mx);
    sc[t] = e0; sc[t + 512] = e1;
    red[t] = e0 + e1; __syncthreads();
    #pragma unroll
    for (int s = 256; s > 0; s >>= 1) {
        if (t < s) red[t] += red[t + s];
        __syncthreads();
    }
    float lsum = red[0]; __syncthreads();
    // wvec[k] = sum_j sc[j] * X[j][k]  (coalesced across lanes per j)
    for (int k = t; k < DD; k += 512) {
        float acc = 0.f;
        #pragma unroll 8
        for (int j = 0; j < SS; ++j)
            acc += sc[j] * Xrow[(size_t)j * DD + k];
        wvec[k] = acc;
    }
    __syncthreads();
    // og[d] = (wvec . Wvg[:, hs+d]) / lsum + bvg[hs+d]
    {
        int d = t & 63, p = t >> 6;
        float acc = 0.f;
        int k0 = p * 96;
        #pragma unroll 8
        for (int k = k0; k < k0 + 96; ++k)
            acc += wvec[k] * Wvg[(size_t)k * DD + hh * 64 + d];
        part[p][d] = acc;
    }
    __syncthreads();
    if (t < 64) {
        float s = 0.f;
        #pragma unroll
        for (int p = 0; p < 8; ++p) s += part[p][t];
        AO[(size_t)(b * SS) * DD + hh * 64 + t] = f2bf(s / lsum + bvg[hh * 64 + t]);
    }
}

// ---------------- head stage A ----------------
__global__ __launch_bounds__(256) void head1_kernel(
    const float* __restrict__ X, const float* __restrict__ motif,
    const float* __restrict__ Wd, float* __restrict__ hpart) {
    __shared__ float hc[HCAT];
    __shared__ float part[4][64];
    int jb = blockIdx.x, kp = blockIdx.y, b = blockIdx.z;
    int t = threadIdx.x;
    for (int i = t; i < DD; i += 256) hc[i] = X[(size_t)b * SS * DD + i];
    for (int i = t; i < MOTIF; i += 256) hc[DD + i] = motif[(size_t)b * MOTIF + i];
    __syncthreads();
    int j = jb * 64 + (t & 63);
    int sub = t >> 6;
    int k0 = kp * 148 + sub * 37;
    int k1 = k0 + 37; if (k1 > HCAT) k1 = HCAT;
    float acc = 0.f;
    for (int k = k0; k < k1; ++k) acc += hc[k] * Wd[(size_t)k * DD + j];
    part[sub][t & 63] = acc;
    __syncthreads();
    if (sub == 0) {
        int x = t & 63;
        hpart[((size_t)b * 8 + kp) * DD + j] = part[0][x] + part[1][x] + part[2][x] + part[3][x];
    }
}

// ---------------- head stage B ----------------
__global__ __launch_bounds__(256) void head2_kernel(
    const float* __restrict__ hpart, const float* __restrict__ bd,
    const float* __restrict__ Wp, const float* __restrict__ bp,
    float* __restrict__ out) {
    __shared__ float dvs[DD];
    __shared__ float red[256];
    int b = blockIdx.x;
    int t = threadIdx.x;
    for (int j = t; j < DD; j += 256) {
        float s = bd[j];
        #pragma unroll
        for (int kp = 0; kp < 8; ++kp) s += hpart[((size_t)b * 8 + kp) * DD + j];
        dvs[j] = tanhf(s);
    }
    __syncthreads();
    float a0 = 0.f, a1 = 0.f;
    for (int k = t; k < DD; k += 256) {
        a0 += dvs[k] * Wp[k * 2 + 0];
        a1 += dvs[k] * Wp[k * 2 + 1];
    }
    a0 = block_reduce_sum(a0, red);
    a1 = block_reduce_sum(a1, red);
    if (t == 0) {
        out[b * 2 + 0] = a0 + bp[0];
        out[b * 2 + 1] = a1 + bp[1];
    }
}

// ---------------- host launch ----------------
extern "C" void kernel_launch(void* const* d_in, const int* in_sizes, int n_in,
                              void* d_out, int out_size, void* d_ws, size_t ws_size,
                              hipStream_t stream) {
    const int*   input_ids = (const int*)d_in[0];
    const int*   attn_mask = (const int*)d_in[1];
    const float* motif     = (const float*)d_in[2];
    const float* emb_word  = (const float*)d_in[3];
    const float* emb_pos   = (const float*)d_in[4];
    const float* emb_type  = (const float*)d_in[5];
    const float* emb_ln_s  = (const float*)d_in[6];
    const float* emb_ln_b  = (const float*)d_in[7];
    const float* Wq  = (const float*)d_in[8];
    const float* bq  = (const float*)d_in[9];
    const float* Wk  = (const float*)d_in[10];
    const float* bk  = (const float*)d_in[11];
    const float* Wv  = (const float*)d_in[12];
    const float* bv  = (const float*)d_in[13];
    const float* Wqg = (const float*)d_in[14];
    const float* bqg = (const float*)d_in[15];
    const float* Wkg = (const float*)d_in[16];
    const float* bkg = (const float*)d_in[17];
    const float* Wvg = (const float*)d_in[18];
    const float* bvg = (const float*)d_in[19];
    const float* Wo  = (const float*)d_in[20];
    const float* bo  = (const float*)d_in[21];
    const float* ln1_s = (const float*)d_in[22];
    const float* ln1_b = (const float*)d_in[23];
    const float* Wi  = (const float*)d_in[24];
    const float* bi  = (const float*)d_in[25];
    const float* Wo2 = (const float*)d_in[26];
    const float* bo2 = (const float*)d_in[27];
    const float* ln2_s = (const float*)d_in[28];
    const float* ln2_b = (const float*)d_in[29];
    const float* head_Wd = (const float*)d_in[30];
    const float* head_bd = (const float*)d_in[31];
    const float* head_Wp = (const float*)d_in[32];
    const float* head_bp = (const float*)d_in[33];

    float* out = (float*)d_out;
    char* base = (char*)d_ws;

    // workspace layout (bytes)
    float* Xf   = (float*)(base + 0);          // [2048][768] f32
    u16*   Xb   = (u16*)  (base + 6291456);    // [2048][768] bf16
    u16*   QKVb = (u16*)  (base + 9437184);    // [2048][2304] bf16 -> 18874368
    u16*   AOb  = (u16*)  (base + 18874368);   // [2048][768] bf16 -> 22020096
    float* T1f  = (float*)(base + 22020096);   // up to 4x [2048][768] f32 -> 47185920

    const size_t NEED_BIG  = 61661184;    // 4 partials + per-layer weights
    const size_t NEED_HUGE = 217214976;   // 4 partials + all-layer weights
    bool huge = ws_size >= NEED_HUGE;
    bool big  = huge || ws_size >= NEED_BIG;
    int NT = big ? 4 : 1;

    u16* WtAll; float* bcat; float* hpart;
    u16 *Wt4_s = nullptr, *Wti_s = nullptr, *Wto2_s = nullptr;
    if (huge) {
        bcat  = (float*)(base + 47185920);
        hpart = (float*)(base + 47296512);
        WtAll = (u16*)  (base + 47345664);   // 12 x WL_ELE u16
    } else {
        size_t wbase = big ? 47345664 : 28311552;
        Wt4_s  = (u16*)(base + wbase);
        Wti_s  = (u16*)(base + wbase + 4718592);
        Wto2_s = (u16*)(base + wbase + 9437184);
        bcat   = (float*)(base + wbase + 14155776);
        hpart  = (float*)(base + wbase + 14266368);
        WtAll  = Wt4_s;
    }
    u16* Hb = QKVb;   // FF intermediate [2048][3072] bf16 aliases QKVb+AOb exactly

    const int nrow = BB * SS;

    embed_ln_kernel<<<nrow, 256, 0, stream>>>(input_ids, emb_word, emb_pos, emb_type,
                                              emb_ln_s, emb_ln_b, Xf, Xb);
    bcat_kernel<<<(LL * LD3 + 255) / 256, 256, 0, stream>>>(bq, bk, bv, bcat);
    if (huge)
        conv_all_kernel<1><<<dim3(1728, 12), 256, 0, stream>>>(
            Wq, Wk, Wv, Wo, Wi, Wo2, WtAll);

    dim3 g3(18, 16, 1);                  // N=2304 batched QKV
    dim3 gO(6, 16, NT);
    dim3 gFF1(24, 16, 1);
    dim3 gFF2(6, 16, NT);

    for (int l = 0; l < LL; ++l) {
        size_t oDD = (size_t)l * DD * DD;
        u16 *Wt4, *Wti, *Wto2;
        if (huge) {
            Wt4  = WtAll + (size_t)l * WL_ELE;
            Wti  = Wt4 + 4 * DD * DD;
            Wto2 = Wti + FFF * DD;
        } else {
            conv_all_kernel<0><<<dim3(1728, 1), 256, 0, stream>>>(
                Wq + oDD, Wk + oDD, Wv + oDD, Wo + oDD,
                Wi + (size_t)l * DD * FFF, Wo2 + (size_t)l * FFF * DD, Wt4_s);
            Wt4 = Wt4_s; Wti = Wti_s; Wto2 = Wto2_s;
        }

        gemm_bf16<0, 1><<<g3, 256, 0, stream>>>(Xb, Wt4, bcat + l * LD3, QKVb,
                                                nrow, LD3, DD, DD);

        attn_local_mfma<<<BB * HH * 16, 256, 0, stream>>>(QKVb, attn_mask, AOb);
        attn_global_kernel<<<BB * HH, 512, 0, stream>>>(
            Xf, Wqg + oDD, bqg + l * DD, Wkg + oDD, bkg + l * DD,
            Wvg + oDD, bvg + l * DD, attn_mask, AOb);

        gemm_bf16<0, 0><<<gO, 256, 0, stream>>>(AOb, Wt4 + 3 * (size_t)DD * DD, bo + l * DD,
                                                T1f, nrow, DD, DD, DD / NT);
        add_ln_kernel<<<nrow, 256, 0, stream>>>(Xf, Xb, T1f, NT,
                                                ln1_s + l * DD, ln1_b + l * DD);

        gemm_bf16<1, 1><<<gFF1, 256, 0, stream>>>(Xb, Wti, bi + l * FFF, Hb,
                                                  nrow, FFF, DD, DD);
        gemm_bf16<0, 0><<<gFF2, 256, 0, stream>>>(Hb, Wto2, bo2 + l * DD,
                                                  T1f, nrow, DD, FFF, FFF / NT);
        add_ln_kernel<<<nrow, 256, 0, stream>>>(Xf, Xb, T1f, NT,
                                                ln2_s + l * DD, ln2_b + l * DD);
    }

    head1_kernel<<<dim3(12, 8, BB), 256, 0, stream>>>(Xf, motif, head_Wd, hpart);
    head2_kernel<<<BB, 256, 0, stream>>>(hpart, head_bd, head_Wp, head_bp, out);
}

// Round 16
// 2399.584 us; speedup vs baseline: 1.7972x; 1.7972x over previous
//
#include <hip/hip_runtime.h>
#include <math.h>

typedef unsigned short u16;
typedef __attribute__((ext_vector_type(8))) short short8;   // 8 bf16 (4 VGPRs)
typedef __attribute__((ext_vector_type(4))) float f32x4;

#define BB 2
#define SS 1024
#define LL 12
#define HH 12
#define DD 768
#define FFF 3072
#define MOTIF 414
#define HCAT (DD + MOTIF)
#define W1 256
#define NEGV -1e9f
#define EPS 1e-5f
#define SCALE 0.125f
#define LD5 3840            // 5*768, QKV buffer row stride
#define WL_ELE 8257536      // u16 elements of one layer's converted weights (16515072 B)

// ---------- bf16 helpers ----------
__device__ __forceinline__ float bf2f(u16 u) {
    union { unsigned i; float f; } x; x.i = ((unsigned)u) << 16; return x.f;
}
__device__ __forceinline__ u16 f2bf(float f) {
    union { float f; unsigned i; } x; x.f = f;
    unsigned r = x.i + 0x7fffu + ((x.i >> 16) & 1u);   // RNE
    return (u16)(r >> 16);
}

// async global->LDS, 16B per lane; lds dest must be wave-uniform base
__device__ __forceinline__ void gld16(const u16* g, u16* l) {
    __builtin_amdgcn_global_load_lds((const __attribute__((address_space(1))) void*)g,
                                     (__attribute__((address_space(3))) void*)l, 16, 0, 0);
}

// ---------------- block reduction helper (blockDim.x == 256) ----------------
__device__ __forceinline__ float block_reduce_sum(float v, float* red) {
    int t = threadIdx.x;
    red[t] = v; __syncthreads();
    #pragma unroll
    for (int s = 128; s > 0; s >>= 1) {
        if (t < s) red[t] += red[t + s];
        __syncthreads();
    }
    float r = red[0]; __syncthreads();
    return r;
}

// ---------------- embedding + LN (writes f32 X and bf16 Xb) ----------------
__global__ __launch_bounds__(256) void embed_ln_kernel(
    const int* __restrict__ ids, const float* __restrict__ ew,
    const float* __restrict__ ep, const float* __restrict__ et,
    const float* __restrict__ gs, const float* __restrict__ gb,
    float* __restrict__ X, u16* __restrict__ Xb) {
    __shared__ float red[256];
    int row = blockIdx.x;
    int s = row % SS;
    int id = ids[row];
    int t = threadIdx.x;
    float v[3];
    float sum = 0.f;
    #pragma unroll
    for (int i = 0; i < 3; ++i) {
        int d = t + 256 * i;
        float x = ew[(size_t)id * DD + d] + ep[(size_t)(s + 2) * DD + d] + et[d];
        v[i] = x; sum += x;
    }
    sum = block_reduce_sum(sum, red);
    float m = sum * (1.f / DD);
    float sq = 0.f;
    #pragma unroll
    for (int i = 0; i < 3; ++i) { float c = v[i] - m; sq += c * c; }
    sq = block_reduce_sum(sq, red);
    float inv = rsqrtf(sq * (1.f / DD) + EPS);
    #pragma unroll
    for (int i = 0; i < 3; ++i) {
        int d = t + 256 * i;
        float o = (v[i] - m) * inv * gs[d] + gb[d];
        X[(size_t)row * DD + d] = o;
        Xb[(size_t)row * DD + d] = f2bf(o);
    }
}

// ---------------- residual add + LN: X = LN(X + sum_{p<NT} T[p]); writes f32 + bf16 ----
__global__ __launch_bounds__(256) void add_ln_kernel(
    float* __restrict__ X, u16* __restrict__ Xb,
    const float* __restrict__ Tbase, int NT,
    const float* __restrict__ gs, const float* __restrict__ gb) {
    __shared__ float red[256];
    int row = blockIdx.x;
    int t = threadIdx.x;
    const size_t MN = (size_t)BB * SS * DD;
    float v[3];
    float sum = 0.f;
    #pragma unroll
    for (int i = 0; i < 3; ++i) {
        int d = t + 256 * i;
        size_t idx = (size_t)row * DD + d;
        float x = X[idx];
        for (int p = 0; p < NT; ++p) x += Tbase[p * MN + idx];
        v[i] = x; sum += x;
    }
    sum = block_reduce_sum(sum, red);
    float m = sum * (1.f / DD);
    float sq = 0.f;
    #pragma unroll
    for (int i = 0; i < 3; ++i) { float c = v[i] - m; sq += c * c; }
    sq = block_reduce_sum(sq, red);
    float inv = rsqrtf(sq * (1.f / DD) + EPS);
    #pragma unroll
    for (int i = 0; i < 3; ++i) {
        int d = t + 256 * i;
        float o = (v[i] - m) * inv * gs[d] + gb[d];
        X[(size_t)row * DD + d] = o;
        Xb[(size_t)row * DD + d] = f2bf(o);
    }
}

// ---------------- weight convert+transpose, 64k x 64n tile per block ----------------
// tiles: [0,864) six DDxDD -> Wt6 ; [864,1440) Wi -> Wti[3072][768] ;
// [1440,2016) Wo2 -> Wto2[768][3072].  blockIdx.y = layer (LAYERED) or 0.
template <int LAYERED>
__global__ __launch_bounds__(256) void conv_all_kernel(
    const float* __restrict__ Wqp, const float* __restrict__ Wkp,
    const float* __restrict__ Wvp, const float* __restrict__ Wkgp,
    const float* __restrict__ Wvgp, const float* __restrict__ Wop,
    const float* __restrict__ Wip, const float* __restrict__ Wo2p,
    u16* __restrict__ WtBase) {
    __shared__ float Tt[64][65];
    int l = LAYERED ? blockIdx.y : 0;
    size_t oDD = (size_t)l * DD * DD;
    size_t oFF = (size_t)l * DD * FFF;
    u16* Wt6  = WtBase + (size_t)l * WL_ELE;
    u16* Wti  = Wt6 + 6 * DD * DD;
    u16* Wto2 = Wti + FFF * DD;
    int tid = blockIdx.x;
    const float* W; u16* Wt; int Nd, Kd, n0, k0;
    if (tid < 864) {
        int z = tid / 144, rem = tid % 144;
        const float* w6[6] = {Wqp + oDD, Wkp + oDD, Wvp + oDD, Wkgp + oDD, Wvgp + oDD, Wop + oDD};
        W = w6[z];
        Wt = Wt6 + (size_t)z * DD * DD;
        Nd = DD; Kd = DD; n0 = (rem % 12) * 64; k0 = (rem / 12) * 64;
    } else if (tid < 1440) {
        int i = tid - 864;
        W = Wip + oFF; Wt = Wti; Nd = FFF; Kd = DD; n0 = (i % 48) * 64; k0 = (i / 48) * 64;
    } else {
        int i = tid - 1440;
        W = Wo2p + oFF; Wt = Wto2; Nd = DD; Kd = FFF; n0 = (i % 12) * 64; k0 = (i / 12) * 64;
    }
    int t = threadIdx.x;
    {
        int rbase = t >> 4, c = (t & 15) * 4;
        #pragma unroll
        for (int i = 0; i < 4; ++i) {
            int r = rbase + i * 16;
            float4 v = *(const float4*)(W + (size_t)(k0 + r) * Nd + n0 + c);
            Tt[r][c + 0] = v.x; Tt[r][c + 1] = v.y;
            Tt[r][c + 2] = v.z; Tt[r][c + 3] = v.w;
        }
    }
    __syncthreads();
    {
        int nbase = t >> 3, kk = (t & 7) * 8;
        #pragma unroll
        for (int i = 0; i < 2; ++i) {
            int n = nbase + i * 32;
            union { uint4 v; u16 e[8]; } wv;
            #pragma unroll
            for (int j = 0; j < 8; ++j) wv.e[j] = f2bf(Tt[kk + j][n]);
            *(uint4*)&Wt[(size_t)(n0 + n) * Kd + k0 + kk] = wv.v;
        }
    }
}

// ---------------- bias concat for batched QKV gemm: bcat[l][5*768] ----------------
__global__ __launch_bounds__(256) void bcat_kernel(
    const float* __restrict__ bq, const float* __restrict__ bk,
    const float* __restrict__ bv, const float* __restrict__ bkg,
    const float* __restrict__ bvg, float* __restrict__ bcat) {
    int tid = blockIdx.x * 256 + threadIdx.x;
    if (tid >= LL * LD5) return;
    int l = tid / LD5, r = tid % LD5, z = r / DD, j = r % DD;
    const float* src = (z == 0) ? bq : (z == 1) ? bk : (z == 2) ? bv : (z == 3) ? bkg : bvg;
    bcat[tid] = src[l * DD + j];
}

// ---------------- bf16 MFMA GEMM, 2-deep counted-vmcnt pipeline (R8-proven) ----------
#define STAGE(j, buf)                                                                   \
    do {                                                                                \
        int _k0 = (j) << 5;                                                             \
        _Pragma("unroll")                                                               \
        for (int _op = 0; _op < 2; ++_op) {                                             \
            int _rc = rA + _op * 16;                                                    \
            int _r = _rc + rr;                                                          \
            gld16(A  + (size_t)(bm + _r) * K + kbeg + _k0 + ((s4 ^ (_r & 3)) * 8),      \
                  &As[buf][_rc * 32]);                                                  \
            gld16(Bt + (size_t)(bn + _r) * K + kbeg + _k0 + ((s4 ^ (_r & 3)) * 8),      \
                  &Bs[buf][_rc * 32]);                                                  \
        }                                                                               \
    } while (0)

template <int ACT, int OBF>
__global__ __launch_bounds__(256) void gemm_bf16(
    const u16* __restrict__ A, const u16* __restrict__ Bt,
    const float* __restrict__ bias, void* __restrict__ Cout,
    int M, int N, int K, int Ksplit) {
    __shared__ __align__(16) u16 As[2][128 * 32];
    __shared__ __align__(16) u16 Bs[2][128 * 32];
    int z = blockIdx.z;
    int kbeg = z * Ksplit;
    int kend = kbeg + Ksplit; if (kend > K) kend = K;
    int t = threadIdx.x, lane = t & 63, wv = t >> 6;
    int bm = blockIdx.y * 128, bn = blockIdx.x * 128;
    int wm = wv >> 1, wn = wv & 1;
    int h = lane >> 4, q15 = lane & 15;
    int rA = wv * 32;
    int rr = lane >> 2, s4 = lane & 3;
    f32x4 acc[4][4];
    #pragma unroll
    for (int i = 0; i < 4; ++i)
        #pragma unroll
        for (int j = 0; j < 4; ++j) { acc[i][j][0] = 0.f; acc[i][j][1] = 0.f; acc[i][j][2] = 0.f; acc[i][j][3] = 0.f; }

    int nk = (kend - kbeg) >> 5;
    STAGE(0, 0);
    if (nk > 1) STAGE(1, 1);
    int cur = 0;
    for (int i = 0; i < nk - 1; ++i) {
        asm volatile("s_waitcnt vmcnt(4)" ::: "memory");
        __builtin_amdgcn_s_barrier();
        short8 af[4], bfr[4];
        #pragma unroll
        for (int mf = 0; mf < 4; ++mf) {
            int row = wm * 64 + mf * 16 + q15;
            af[mf] = *(const short8*)&As[cur][row * 32 + ((h ^ (row & 3)) * 8)];
        }
        #pragma unroll
        for (int nf = 0; nf < 4; ++nf) {
            int row = wn * 64 + nf * 16 + q15;
            bfr[nf] = *(const short8*)&Bs[cur][row * 32 + ((h ^ (row & 3)) * 8)];
        }
        asm volatile("s_waitcnt lgkmcnt(0)" ::: "memory");
        __builtin_amdgcn_sched_barrier(0);
        __builtin_amdgcn_s_barrier();
        __builtin_amdgcn_sched_barrier(0);
        if (i + 2 < nk) STAGE(i + 2, cur);
        #pragma unroll
        for (int mf = 0; mf < 4; ++mf)
            #pragma unroll
            for (int nf = 0; nf < 4; ++nf)
                acc[mf][nf] = __builtin_amdgcn_mfma_f32_16x16x32_bf16(af[mf], bfr[nf], acc[mf][nf], 0, 0, 0);
        cur ^= 1;
    }
    asm volatile("s_waitcnt vmcnt(0)" ::: "memory");
    __builtin_amdgcn_s_barrier();
    {
        short8 af[4], bfr[4];
        #pragma unroll
        for (int mf = 0; mf < 4; ++mf) {
            int row = wm * 64 + mf * 16 + q15;
            af[mf] = *(const short8*)&As[cur][row * 32 + ((h ^ (row & 3)) * 8)];
        }
        #pragma unroll
        for (int nf = 0; nf < 4; ++nf) {
            int row = wn * 64 + nf * 16 + q15;
            bfr[nf] = *(const short8*)&Bs[cur][row * 32 + ((h ^ (row & 3)) * 8)];
        }
        #pragma unroll
        for (int mf = 0; mf < 4; ++mf)
            #pragma unroll
            for (int nf = 0; nf < 4; ++nf)
                acc[mf][nf] = __builtin_amdgcn_mfma_f32_16x16x32_bf16(af[mf], bfr[nf], acc[mf][nf], 0, 0, 0);
    }
    float* Cf = (float*)Cout + (size_t)z * M * N;
    u16*   Cb = (u16*)Cout;
    #pragma unroll
    for (int mf = 0; mf < 4; ++mf) {
        int mbase = bm + wm * 64 + mf * 16 + h * 4;
        #pragma unroll
        for (int nf = 0; nf < 4; ++nf) {
            int n = bn + wn * 64 + nf * 16 + q15;
            float bv = 0.f;
            if (z == 0) bv = bias[n];
            #pragma unroll
            for (int rg = 0; rg < 4; ++rg) {
                float val = acc[mf][nf][rg] + bv;
                if (ACT == 1) val = 0.5f * val * (1.f + erff(val * 0.70710678118654752f));
                if (OBF) Cb[(size_t)(mbase + rg) * N + n] = f2bf(val);
                else     Cf[(size_t)(mbase + rg) * N + n] = val;
            }
        }
    }
}

// ---------------- fused local-window flash attention (MFMA), R8-proven ----------------
__global__ __launch_bounds__(256) void attn_local_mfma(
    const u16* __restrict__ QKV, const int* __restrict__ mask,
    u16* __restrict__ AO) {
    __shared__ __align__(16) u16 Qs[64 * 64];
    __shared__ __align__(16) u16 Ks[64 * 64];
    __shared__ __align__(16) u16 Vst[64 * 64];
    __shared__ __align__(16) u16 Pld[4][16 * 64];
    __shared__ float msk[64];
    int bid = blockIdx.x;
    int qt = bid & 15;
    int hh = (bid >> 4) % HH;
    int b  = bid / (16 * HH);
    int t = threadIdx.x, lane = t & 63, wv = t >> 6;
    int h = lane >> 4, q15 = lane & 15;
    int i0 = qt * 64;

    #pragma unroll
    for (int op = 0; op < 2; ++op) {
        int r = wv * 16 + op * 8 + (lane >> 3), s = lane & 7;
        gld16(QKV + (size_t)(b * SS + i0 + r) * LD5 + hh * 64 + ((s ^ (r & 7)) * 8),
              &Qs[(wv * 16 + op * 8) * 64]);
    }
    __syncthreads();
    short8 bq[2];
    {
        int qrow = wv * 16 + q15;
        #pragma unroll
        for (int ks = 0; ks < 2; ++ks)
            bq[ks] = *(const short8*)&Qs[qrow * 64 + (((ks * 4 + h) ^ (qrow & 7)) * 8)];
    }

    float mrun = -3e38f, lrun = 0.f;
    f32x4 o[4];
    #pragma unroll
    for (int nf = 0; nf < 4; ++nf) { o[nf][0] = 0.f; o[nf][1] = 0.f; o[nf][2] = 0.f; o[nf][3] = 0.f; }

    int jlo = i0 - W1; if (jlo < 0) jlo = 0;
    int jend = i0 + 64 + W1; if (jend > SS) jend = SS;
    int hasCLS = (jlo > 0) ? 1 : 0;
    int nt = hasCLS + (jend - jlo) / 64;
    int iq = i0 + wv * 16 + q15;

    for (int tt = 0; tt < nt; ++tt) {
        int base = (hasCLS && tt == 0) ? 0 : jlo + (tt - hasCLS) * 64;
        if (tt > 0) __syncthreads();
        #pragma unroll
        for (int op = 0; op < 2; ++op) {
            int r = wv * 16 + op * 8 + (lane >> 3), s = lane & 7;
            gld16(QKV + (size_t)(b * SS + base + r) * LD5 + 768 + hh * 64 + ((s ^ (r & 7)) * 8),
                  &Ks[(wv * 16 + op * 8) * 64]);
        }
        {
            int k2 = t & 31, dsec = t >> 5;
            const u16* vp = QKV + (size_t)(b * SS + base + 2 * k2) * LD5 + 1536 + hh * 64 + dsec * 8;
            union { uint4 v; u16 e[8]; } r0, r1;
            r0.v = *(const uint4*)vp;
            r1.v = *(const uint4*)(vp + LD5);
            int slot = k2 >> 2;
            #pragma unroll
            for (int j = 0; j < 8; ++j) {
                int d = dsec * 8 + j;
                unsigned val = (unsigned)r0.e[j] | ((unsigned)r1.e[j] << 16);
                *(unsigned*)&Vst[d * 64 + ((slot ^ (d & 7)) * 8) + ((2 * k2) & 7)] = val;
            }
        }
        if (t < 64) msk[t] = (float)mask[b * SS + base + t];
        __syncthreads();

        f32x4 sacc[4];
        #pragma unroll
        for (int kf = 0; kf < 4; ++kf) { sacc[kf][0] = 0.f; sacc[kf][1] = 0.f; sacc[kf][2] = 0.f; sacc[kf][3] = 0.f; }
        #pragma unroll
        for (int ks = 0; ks < 2; ++ks) {
            #pragma unroll
            for (int kf = 0; kf < 4; ++kf) {
                int krow = kf * 16 + q15;
                short8 afr = *(const short8*)&Ks[krow * 64 + (((ks * 4 + h) ^ (krow & 7)) * 8)];
                sacc[kf] = __builtin_amdgcn_mfma_f32_16x16x32_bf16(afr, bq[ks], sacc[kf], 0, 0, 0);
            }
        }
        float pv[4][4];
        float tmax = -3e38f;
        #pragma unroll
        for (int kf = 0; kf < 4; ++kf) {
            #pragma unroll
            for (int rg = 0; rg < 4; ++rg) {
                int kl = kf * 16 + h * 4 + rg;
                int key = base + kl;
                int dj = iq - key; int adj = dj < 0 ? -dj : dj;
                bool valid = ((adj <= W1) || (key == 0)) && (msk[kl] != 0.f);
                float s = valid ? sacc[kf][rg] * SCALE : NEGV;
                pv[kf][rg] = s;
                tmax = fmaxf(tmax, s);
            }
        }
        tmax = fmaxf(tmax, __shfl_xor(tmax, 16));
        tmax = fmaxf(tmax, __shfl_xor(tmax, 32));
        float mnew = fmaxf(mrun, tmax);
        float fac = __expf(mrun - mnew);
        mrun = mnew;
        float psum = 0.f;
        #pragma unroll
        for (int kf = 0; kf < 4; ++kf)
            #pragma unroll
            for (int rg = 0; rg < 4; ++rg) {
                float p = __expf(pv[kf][rg] - mnew);
                pv[kf][rg] = p; psum += p;
            }
        psum += __shfl_xor(psum, 16);
        psum += __shfl_xor(psum, 32);
        lrun = lrun * fac + psum;
        #pragma unroll
        for (int kf = 0; kf < 4; ++kf) {
            unsigned lo = (unsigned)f2bf(pv[kf][0]) | ((unsigned)f2bf(pv[kf][1]) << 16);
            unsigned hi = (unsigned)f2bf(pv[kf][2]) | ((unsigned)f2bf(pv[kf][3]) << 16);
            int slot = 2 * kf + (h >> 1);
            uint2 w; w.x = lo; w.y = hi;
            *(uint2*)&Pld[wv][q15 * 64 + ((slot ^ (q15 & 7)) * 8) + 4 * (h & 1)] = w;
        }
        float fo0 = __shfl(fac, (h * 4 + 0) | (lane & 48));
        float fo1 = __shfl(fac, (h * 4 + 1) | (lane & 48));
        float fo2 = __shfl(fac, (h * 4 + 2) | (lane & 48));
        float fo3 = __shfl(fac, (h * 4 + 3) | (lane & 48));
        #pragma unroll
        for (int nf = 0; nf < 4; ++nf) {
            o[nf][0] *= fo0; o[nf][1] *= fo1; o[nf][2] *= fo2; o[nf][3] *= fo3;
        }
        asm volatile("s_waitcnt lgkmcnt(0)" ::: "memory");
        #pragma unroll
        for (int ks = 0; ks < 2; ++ks) {
            short8 ap = *(const short8*)&Pld[wv][q15 * 64 + (((ks * 4 + h) ^ (q15 & 7)) * 8)];
            #pragma unroll
            for (int nf = 0; nf < 4; ++nf) {
                int d = nf * 16 + q15;
                short8 bvf = *(const short8*)&Vst[d * 64 + (((ks * 4 + h) ^ (d & 7)) * 8)];
                o[nf] = __builtin_amdgcn_mfma_f32_16x16x32_bf16(ap, bvf, o[nf], 0, 0, 0);
            }
        }
    }
    float linv = 1.f / lrun;
    float g0 = __shfl(linv, (h * 4 + 0) | (lane & 48));
    float g1 = __shfl(linv, (h * 4 + 1) | (lane & 48));
    float g2 = __shfl(linv, (h * 4 + 2) | (lane & 48));
    float g3 = __shfl(linv, (h * 4 + 3) | (lane & 48));
    size_t rb = (size_t)(b * SS + i0 + wv * 16 + h * 4);
    #pragma unroll
    for (int nf = 0; nf < 4; ++nf) {
        int d = hh * 64 + nf * 16 + q15;
        AO[(rb + 0) * DD + d] = f2bf(o[nf][0] * g0);
        AO[(rb + 1) * DD + d] = f2bf(o[nf][1] * g1);
        AO[(rb + 2) * DD + d] = f2bf(o[nf][2] * g2);
        AO[(rb + 3) * DD + d] = f2bf(o[nf][3] * g3);
    }
}

// ---------------- global (CLS) attention, qg GEMV fused, 512 threads ----------------
__global__ __launch_bounds__(512) void attn_global_kernel(
    const float* __restrict__ Xf, const float* __restrict__ Wqg,
    const float* __restrict__ bqg, const u16* __restrict__ QKV,
    const int* __restrict__ mask, u16* __restrict__ AO) {
    __shared__ float x0[DD];
    __shared__ float qv[64];
    __shared__ float sc[SS];
    __shared__ float red[512];
    __shared__ float part[8][64];
    int b = blockIdx.x / HH, hh = blockIdx.x % HH;
    int t = threadIdx.x;
    for (int i = t; i < DD; i += 512) x0[i] = Xf[(size_t)b * SS * DD + i];
    __syncthreads();
    {
        int d = t & 63, p = t >> 6;
        float acc = 0.f;
        int k0 = p * 96;
        #pragma unroll 8
        for (int k = k0; k < k0 + 96; ++k)
            acc += x0[k] * Wqg[(size_t)k * DD + hh * 64 + d];
        part[p][d] = acc;
    }
    __syncthreads();
    if (t < 64) {
        float s = bqg[hh * 64 + t];
        #pragma unroll
        for (int p = 0; p < 8; ++p) s += part[p][t];
        qv[t] = s * SCALE;
    }
    __syncthreads();
    for (int j = t; j < SS; j += 512) {
        const u16* kp = QKV + (size_t)(b * SS + j) * LD5 + 2304 + hh * 64;
        float acc = 0.f;
        #pragma unroll
        for (int d0 = 0; d0 < 64; d0 += 8) {
            union { uint4 v; u16 e[8]; } u;
            u.v = *(const uint4*)(kp + d0);
            #pragma unroll
            for (int j2 = 0; j2 < 8; ++j2) acc += qv[d0 + j2] * bf2f(u.e[j2]);
        }
        sc[j] = mask[b * SS + j] ? acc : NEGV;
    }
    __syncthreads();
    float mx = fmaxf(sc[t], sc[t + 512]);
    red[t] = mx; __syncthreads();
    #pragma unroll
    for (int s = 256; s > 0; s >>= 1) {
        if (t < s) red[t] = fmaxf(red[t], red[t + s]);
        __syncthreads();
    }
    mx = red[0]; __syncthreads();
    float e0 = __expf(sc[t] - mx), e1 = __expf(sc[t + 512] - mx);
    sc[t] = e0; sc[t + 512] = e1;
    red[t] = e0 + e1; __syncthreads();
    #pragma unroll
    for (int s = 256; s > 0; s >>= 1) {
        if (t < s) red[t] += red[t + s];
        __syncthreads();
    }
    float lsum = red[0]; __syncthreads();
    int g = t >> 6, d = t & 63;
    float acc = 0.f;
    for (int j = g; j < SS; j += 8)
        acc += sc[j] * bf2f(QKV[(size_t)(b * SS + j) * LD5 + 3072 + hh * 64 + d]);
    part[g][d] = acc;
    __syncthreads();
    if (g == 0) {
        float ov = 0.f;
        #pragma unroll
        for (int p = 0; p < 8; ++p) ov += part[p][d];
        AO[(size_t)(b * SS) * DD + hh * 64 + d] = f2bf(ov / lsum);
    }
}

// ---------------- head stage A ----------------
__global__ __launch_bounds__(256) void head1_kernel(
    const float* __restrict__ X, const float* __restrict__ motif,
    const float* __restrict__ Wd, float* __restrict__ hpart) {
    __shared__ float hc[HCAT];
    __shared__ float part[4][64];
    int jb = blockIdx.x, kp = blockIdx.y, b = blockIdx.z;
    int t = threadIdx.x;
    for (int i = t; i < DD; i += 256) hc[i] = X[(size_t)b * SS * DD + i];
    for (int i = t; i < MOTIF; i += 256) hc[DD + i] = motif[(size_t)b * MOTIF + i];
    __syncthreads();
    int j = jb * 64 + (t & 63);
    int sub = t >> 6;
    int k0 = kp * 148 + sub * 37;
    int k1 = k0 + 37; if (k1 > HCAT) k1 = HCAT;
    float acc = 0.f;
    for (int k = k0; k < k1; ++k) acc += hc[k] * Wd[(size_t)k * DD + j];
    part[sub][t & 63] = acc;
    __syncthreads();
    if (sub == 0) {
        int x = t & 63;
        hpart[((size_t)b * 8 + kp) * DD + j] = part[0][x] + part[1][x] + part[2][x] + part[3][x];
    }
}

// ---------------- head stage B ----------------
__global__ __launch_bounds__(256) void head2_kernel(
    const float* __restrict__ hpart, const float* __restrict__ bd,
    const float* __restrict__ Wp, const float* __restrict__ bp,
    float* __restrict__ out) {
    __shared__ float dvs[DD];
    __shared__ float red[256];
    int b = blockIdx.x;
    int t = threadIdx.x;
    for (int j = t; j < DD; j += 256) {
        float s = bd[j];
        #pragma unroll
        for (int kp = 0; kp < 8; ++kp) s += hpart[((size_t)b * 8 + kp) * DD + j];
        dvs[j] = tanhf(s);
    }
    __syncthreads();
    float a0 = 0.f, a1 = 0.f;
    for (int k = t; k < DD; k += 256) {
        a0 += dvs[k] * Wp[k * 2 + 0];
        a1 += dvs[k] * Wp[k * 2 + 1];
    }
    a0 = block_reduce_sum(a0, red);
    a1 = block_reduce_sum(a1, red);
    if (t == 0) {
        out[b * 2 + 0] = a0 + bp[0];
        out[b * 2 + 1] = a1 + bp[1];
    }
}

// ---------------- host launch ----------------
extern "C" void kernel_launch(void* const* d_in, const int* in_sizes, int n_in,
                              void* d_out, int out_size, void* d_ws, size_t ws_size,
                              hipStream_t stream) {
    const int*   input_ids = (const int*)d_in[0];
    const int*   attn_mask = (const int*)d_in[1];
    const float* motif     = (const float*)d_in[2];
    const float* emb_word  = (const float*)d_in[3];
    const float* emb_pos   = (const float*)d_in[4];
    const float* emb_type  = (const float*)d_in[5];
    const float* emb_ln_s  = (const float*)d_in[6];
    const float* emb_ln_b  = (const float*)d_in[7];
    const float* Wq  = (const float*)d_in[8];
    const float* bq  = (const float*)d_in[9];
    const float* Wk  = (const float*)d_in[10];
    const float* bk  = (const float*)d_in[11];
    const float* Wv  = (const float*)d_in[12];
    const float* bv  = (const float*)d_in[13];
    const float* Wqg = (const float*)d_in[14];
    const float* bqg = (const float*)d_in[15];
    const float* Wkg = (const float*)d_in[16];
    const float* bkg = (const float*)d_in[17];
    const float* Wvg = (const float*)d_in[18];
    const float* bvg = (const float*)d_in[19];
    const float* Wo  = (const float*)d_in[20];
    const float* bo  = (const float*)d_in[21];
    const float* ln1_s = (const float*)d_in[22];
    const float* ln1_b = (const float*)d_in[23];
    const float* Wi  = (const float*)d_in[24];
    const float* bi  = (const float*)d_in[25];
    const float* Wo2 = (const float*)d_in[26];
    const float* bo2 = (const float*)d_in[27];
    const float* ln2_s = (const float*)d_in[28];
    const float* ln2_b = (const float*)d_in[29];
    const float* head_Wd = (const float*)d_in[30];
    const float* head_bd = (const float*)d_in[31];
    const float* head_Wp = (const float*)d_in[32];
    const float* head_bp = (const float*)d_in[33];

    float* out = (float*)d_out;
    char* base = (char*)d_ws;

    // fixed workspace
    float* Xf   = (float*)(base + 0);          // [2048][768] f32
    u16*   Xb   = (u16*)  (base + 6291456);    // [2048][768] bf16
    u16*   QKVb = (u16*)  (base + 9437184);    // [2048][3840] bf16
    u16*   AOb  = (u16*)  (base + 25165824);   // [2048][768] bf16
    float* T1f  = (float*)(base + 28311552);   // up to 4x [2048][768] f32 partials

    const size_t NEED_BIG  = 70225920;    // 4 partials + per-layer weights
    const size_t NEED_HUGE = 251891712;   // 4 partials + all-layer weights
    bool huge = ws_size >= NEED_HUGE;
    bool big  = huge || ws_size >= NEED_BIG;
    int NT = big ? 4 : 1;

    u16* WtAll; float* bcat; float* hpart;
    u16 *Wt6_s = nullptr, *Wti_s = nullptr, *Wto2_s = nullptr;
    if (huge) {
        bcat  = (float*)(base + 53477376);
        hpart = (float*)(base + 53661696);
        WtAll = (u16*)  (base + 53710848);   // 12 x WL_ELE u16
    } else {
        size_t wbase = big ? 53710848 : 34603008;
        Wt6_s  = (u16*)(base + wbase);
        Wti_s  = (u16*)(base + wbase + 7077888);
        Wto2_s = (u16*)(base + wbase + 11796480);
        bcat   = (float*)(base + wbase + 16515072);
        hpart  = (float*)(base + wbase + 16699392);
        WtAll  = Wt6_s;
    }
    u16* Hb = QKVb;   // FF intermediate aliases QKV

    const int nrow = BB * SS;

    embed_ln_kernel<<<nrow, 256, 0, stream>>>(input_ids, emb_word, emb_pos, emb_type,
                                              emb_ln_s, emb_ln_b, Xf, Xb);
    bcat_kernel<<<(LL * LD5 + 255) / 256, 256, 0, stream>>>(bq, bk, bv, bkg, bvg, bcat);
    if (huge)
        conv_all_kernel<1><<<dim3(2016, 12), 256, 0, stream>>>(
            Wq, Wk, Wv, Wkg, Wvg, Wo, Wi, Wo2, WtAll);

    dim3 g5(30, 16, 1);
    dim3 gO(6, 16, NT);
    dim3 gFF1(24, 16, 1);
    dim3 gFF2(6, 16, NT);

    for (int l = 0; l < LL; ++l) {
        size_t oDD = (size_t)l * DD * DD;
        u16 *Wt6, *Wti, *Wto2;
        if (huge) {
            Wt6  = WtAll + (size_t)l * WL_ELE;
            Wti  = Wt6 + 6 * DD * DD;
            Wto2 = Wti + FFF * DD;
        } else {
            conv_all_kernel<0><<<dim3(2016, 1), 256, 0, stream>>>(
                Wq + oDD, Wk + oDD, Wv + oDD, Wkg + oDD, Wvg + oDD, Wo + oDD,
                Wi + (size_t)l * DD * FFF, Wo2 + (size_t)l * FFF * DD, Wt6_s);
            Wt6 = Wt6_s; Wti = Wti_s; Wto2 = Wto2_s;
        }

        gemm_bf16<0, 1><<<g5, 256, 0, stream>>>(Xb, Wt6, bcat + l * LD5, QKVb,
                                                nrow, LD5, DD, DD);

        attn_local_mfma<<<BB * HH * 16, 256, 0, stream>>>(QKVb, attn_mask, AOb);
        attn_global_kernel<<<BB * HH, 512, 0, stream>>>(Xf, Wqg + oDD, bqg + l * DD,
                                                        QKVb, attn_mask, AOb);

        gemm_bf16<0, 0><<<gO, 256, 0, stream>>>(AOb, Wt6 + 5 * (size_t)DD * DD, bo + l * DD,
                                                T1f, nrow, DD, DD, DD / NT);
        add_ln_kernel<<<nrow, 256, 0, stream>>>(Xf, Xb, T1f, NT,
                                                ln1_s + l * DD, ln1_b + l * DD);

        gemm_bf16<1, 1><<<gFF1, 256, 0, stream>>>(Xb, Wti, bi + l * FFF, Hb,
                                                  nrow, FFF, DD, DD);
        gemm_bf16<0, 0><<<gFF2, 256, 0, stream>>>(Hb, Wto2, bo2 + l * DD,
                                                  T1f, nrow, DD, FFF, FFF / NT);
        add_ln_kernel<<<nrow, 256, 0, stream>>>(Xf, Xb, T1f, NT,
                                                ln2_s + l * DD, ln2_b + l * DD);
    }

    head1_kernel<<<dim3(12, 8, BB), 256, 0, stream>>>(Xf, motif, head_Wd, hpart);
    head2_kernel<<<BB, 256, 0, stream>>>(hpart, head_bd, head_Wp, head_bp, out);
}